// Round 1
// baseline (1290.910 us; speedup 1.0000x reference)
//
#include <hip/hip_runtime.h>
#include <cstdint>

#define B_ 32
#define T_ 40
#define P_ 12
#define E_ 2048
#define H_ 1024
#define BP 384      // B_*P_
#define M_ 15360    // B_*T_*P_

typedef _Float16 f16;
typedef _Float16 f16x8 __attribute__((ext_vector_type(8)));
typedef float f32x4 __attribute__((ext_vector_type(4)));

// ---- async global->LDS, 16B per lane (dest = wave-uniform base + lane*16) ----
__device__ __forceinline__ void cp16(const void* g, void* l) {
    auto gp = (const __attribute__((address_space(1))) uint32_t*)(uintptr_t)g;
    auto lp = (__attribute__((address_space(3))) uint32_t*)(uint32_t)(uintptr_t)l;
    __builtin_amdgcn_global_load_lds(gp, lp, 16, 0, 0);
}

__device__ __forceinline__ float fast_tanh(float x) {
    return 1.f - 2.f / (__expf(2.f * x) + 1.f);
}
__device__ __forceinline__ float fast_sig(float x) {
    return 1.f / (1.f + __expf(-x));
}

// ---- fp32 -> fp16 conversion, 8 elems/thread ----
__global__ __launch_bounds__(256) void cvt_f32_f16(const float* __restrict__ in,
                                                   f16* __restrict__ out, int n8) {
    int i = blockIdx.x * 256 + threadIdx.x;
    if (i >= n8) return;
    const float4* in4 = (const float4*)in;
    float4 a = in4[2 * i], b = in4[2 * i + 1];
    f16x8 o = {(f16)a.x, (f16)a.y, (f16)a.z, (f16)a.w,
               (f16)b.x, (f16)b.y, (f16)b.z, (f16)b.w};
    ((f16x8*)out)[i] = o;
}

// ---- 128x128 tile NT-GEMM:  C[m,n] = sum_k A[m,k]*Bm[n,k]  (+bias, epilogue) ----
// EPI 0: out[m*N+n] = (f16)tanh(c+bias[n])            (embed -> x16)
// EPI 1: out[(t*BP + b*12 + p)*N + n] = (f16)(c+bias[n])   (gx, remapped to [T][BP][3H])
template <int EPI>
__global__ __launch_bounds__(256) void gemm128(const f16* __restrict__ A,
                                               const f16* __restrict__ Bm,
                                               const float* __restrict__ bias,
                                               f16* __restrict__ out, int K, int N) {
    __shared__ f16 As[128 * 32];
    __shared__ f16 Bs[128 * 32];
    const int tid = threadIdx.x;
    const int w = tid >> 6, l = tid & 63;
    const int wm = w >> 1, wn = w & 1;      // 2x2 waves of 64x64
    const long arow0 = (long)blockIdx.x * 128;
    const long brow0 = (long)blockIdx.y * 128;
    const int srow = l >> 2, scol = (l & 3) * 8;

    f32x4 acc[4][4] = {};

    for (int k0 = 0; k0 < K; k0 += 32) {
        __syncthreads();
#pragma unroll
        for (int s = 0; s < 2; ++s) {
            int slice = w + s * 4;          // 0..7, wave-uniform
            cp16(A + (arow0 + slice * 16 + srow) * (long)K + k0 + scol,
                 (void*)(As + slice * 512));
            cp16(Bm + (brow0 + slice * 16 + srow) * (long)K + k0 + scol,
                 (void*)(Bs + slice * 512));
        }
        __syncthreads();
        f16x8 af[4], bf[4];
#pragma unroll
        for (int i = 0; i < 4; ++i)
            af[i] = *(const f16x8*)(As + (wm * 64 + i * 16 + (l & 15)) * 32 + (l >> 4) * 8);
#pragma unroll
        for (int j = 0; j < 4; ++j)
            bf[j] = *(const f16x8*)(Bs + (wn * 64 + j * 16 + (l & 15)) * 32 + (l >> 4) * 8);
#pragma unroll
        for (int i = 0; i < 4; ++i)
#pragma unroll
            for (int j = 0; j < 4; ++j)
                acc[i][j] = __builtin_amdgcn_mfma_f32_16x16x32_f16(af[i], bf[j], acc[i][j], 0, 0, 0);
    }

    const int colq = l & 15, rowq = (l >> 4) * 4;
#pragma unroll
    for (int i = 0; i < 4; ++i)
#pragma unroll
        for (int j = 0; j < 4; ++j)
#pragma unroll
            for (int r = 0; r < 4; ++r) {
                long m = arow0 + wm * 64 + i * 16 + rowq + r;
                int n = (int)brow0 + wn * 64 + j * 16 + colq;
                float v = acc[i][j][r] + bias[n];
                if (EPI == 0) {
                    out[m * N + n] = (f16)fast_tanh(v);
                } else {
                    int b = (int)(m / (T_ * P_));
                    int rem = (int)(m % (T_ * P_));
                    int t = rem / P_, p = rem % P_;
                    out[((long)t * BP + b * P_ + p) * N + n] = (f16)v;
                }
            }
}

// ---- fused GRU step: gh = h @ W_hh^T (3 bands) + gates + h update ----
// grid (12, 16): BM=32 rows of h (384 total), BN=64 cols of H
__global__ __launch_bounds__(256) void gru_step(const f16* __restrict__ h16_in,
                                                f16* __restrict__ h16_out,
                                                float* __restrict__ h32,
                                                const f16* __restrict__ Whh,
                                                const float* __restrict__ b_hh,
                                                const f16* __restrict__ gx16,
                                                f16* __restrict__ hid16, int t) {
    __shared__ f16 As[32 * 32];          // h tile
    __shared__ f16 Bs[3 * 64 * 32];      // W_hh, 3 gate bands
    const int tid = threadIdx.x;
    const int w = tid >> 6, l = tid & 63;
    const int m0 = blockIdx.x * 32, n0 = blockIdx.y * 64;
    const int srow = l >> 2, scol = (l & 3) * 8;

    f32x4 acc[3][2] = {};

    for (int k0 = 0; k0 < H_; k0 += 32) {
        __syncthreads();
        if (w < 2)
            cp16(h16_in + (m0 + w * 16 + srow) * H_ + k0 + scol, (void*)(As + w * 512));
#pragma unroll
        for (int q3 = 0; q3 < 3; ++q3) {
            int s = w + q3 * 4;          // 0..11, wave-uniform
            int g = s >> 2, q = s & 3;
            cp16(Whh + (long)(g * H_ + n0 + q * 16 + srow) * H_ + k0 + scol,
                 (void*)(Bs + (g * 64 + q * 16) * 32));
        }
        __syncthreads();
        f16x8 af[2], bf[3];
#pragma unroll
        for (int i = 0; i < 2; ++i)
            af[i] = *(const f16x8*)(As + (i * 16 + (l & 15)) * 32 + (l >> 4) * 8);
#pragma unroll
        for (int g = 0; g < 3; ++g)
            bf[g] = *(const f16x8*)(Bs + (g * 64 + w * 16 + (l & 15)) * 32 + (l >> 4) * 8);
#pragma unroll
        for (int g = 0; g < 3; ++g)
#pragma unroll
            for (int i = 0; i < 2; ++i)
                acc[g][i] = __builtin_amdgcn_mfma_f32_16x16x32_f16(af[i], bf[g], acc[g][i], 0, 0, 0);
    }

    const int col = n0 + w * 16 + (l & 15);
    const long gxbase = (long)t * BP * 3072;
    const float bhr = b_hh[col], bhz = b_hh[H_ + col], bhn = b_hh[2 * H_ + col];
#pragma unroll
    for (int i = 0; i < 2; ++i)
#pragma unroll
        for (int r = 0; r < 4; ++r) {
            int m = m0 + i * 16 + (l >> 4) * 4 + r;
            float hr = acc[0][i][r] + bhr;
            float hz = acc[1][i][r] + bhz;
            float hn = acc[2][i][r] + bhn;
            long gxrow = gxbase + (long)m * 3072;
            float xr = (float)gx16[gxrow + col];
            float xz = (float)gx16[gxrow + H_ + col];
            float xn = (float)gx16[gxrow + 2 * H_ + col];
            float rr = fast_sig(xr + hr);
            float zz = fast_sig(xz + hz);
            float nn = fast_tanh(xn + rr * hn);
            float hp = h32[m * H_ + col];
            float hnew = (1.f - zz) * nn + zz * hp;
            h32[m * H_ + col] = hnew;
            h16_out[m * H_ + col] = (f16)hnew;
            int b = m / P_, p = m % P_;
            hid16[(((long)b * T_ + t) * P_ + p) * H_ + col] = (f16)hnew;
        }
}

// ---- per-(b,t): 12x9 action logits, maxpool over P, 8 activity logits ----
__global__ __launch_bounds__(256) void logits_kernel(const f16* __restrict__ hid16,
                                                     const float* __restrict__ W_act,
                                                     const float* __restrict__ b_act,
                                                     const float* __restrict__ W_activ,
                                                     const float* __restrict__ b_activ,
                                                     float* __restrict__ out) {
    __shared__ f16 hs[P_ * H_];
    __shared__ float pooled[H_];
    const int bt = blockIdx.x;           // b*T_ + t
    const int tid = threadIdx.x, w = tid >> 6, l = tid & 63;

    const f16x8* src = (const f16x8*)(hid16 + (long)bt * P_ * H_);
    f16x8* dst = (f16x8*)hs;
    for (int i = tid; i < P_ * H_ / 8; i += 256) dst[i] = src[i];
    __syncthreads();

    for (int i = tid; i < H_; i += 256) {
        float mx = (float)hs[i];
#pragma unroll
        for (int p = 1; p < P_; ++p) mx = fmaxf(mx, (float)hs[p * H_ + i]);
        pooled[i] = mx;
    }
    __syncthreads();

    // 108 action dot-products
    for (int j = w; j < 108; j += 4) {
        int p = j / 9, a = j % 9;
        float s = 0.f;
#pragma unroll
        for (int it = 0; it < 16; ++it) {
            int idx = l + it * 64;
            s += (float)hs[p * H_ + idx] * W_act[a * H_ + idx];
        }
#pragma unroll
        for (int off = 32; off > 0; off >>= 1) s += __shfl_down(s, off);
        if (l == 0) out[((long)bt * P_ + p) * 9 + a] = s + b_act[a];
    }
    // 8 activity dot-products
    for (int j = w; j < 8; j += 4) {
        float s = 0.f;
#pragma unroll
        for (int it = 0; it < 16; ++it) {
            int idx = l + it * 64;
            s += pooled[idx] * W_activ[j * H_ + idx];
        }
#pragma unroll
        for (int off = 32; off > 0; off >>= 1) s += __shfl_down(s, off);
        if (l == 0) out[(long)M_ * 9 + (long)bt * 8 + j] = s + b_activ[j];
    }
}

extern "C" void kernel_launch(void* const* d_in, const int* in_sizes, int n_in,
                              void* d_out, int out_size, void* d_ws, size_t ws_size,
                              hipStream_t stream) {
    const float* feature = (const float*)d_in[0];
    const float* W_embed = (const float*)d_in[1];
    const float* b_embed = (const float*)d_in[2];
    const float* W_ih    = (const float*)d_in[3];
    const float* W_hh    = (const float*)d_in[4];
    const float* b_ih    = (const float*)d_in[5];
    const float* b_hh    = (const float*)d_in[6];
    const float* W_act   = (const float*)d_in[7];
    const float* b_act   = (const float*)d_in[8];
    const float* W_activ = (const float*)d_in[9];
    const float* b_activ = (const float*)d_in[10];
    float* out = (float*)d_out;

    char* ws = (char*)d_ws;
    size_t off = 0;
    auto alloc = [&](size_t bytes) {
        void* p = ws + off;
        off = (off + bytes + 255) & ~(size_t)255;
        return p;
    };
    f16*   feat16 = (f16*)alloc((size_t)M_ * E_ * 2);        // 62.9 MB
    f16*   wE16   = (f16*)alloc((size_t)H_ * E_ * 2);        //  4.2 MB
    f16*   wIH16  = (f16*)alloc((size_t)3 * H_ * H_ * 2);    //  6.3 MB
    f16*   wHH16  = (f16*)alloc((size_t)3 * H_ * H_ * 2);    //  6.3 MB
    f16*   x16    = (f16*)alloc((size_t)M_ * H_ * 2);        // 31.5 MB
    f16*   gx16   = (f16*)alloc((size_t)M_ * 3 * H_ * 2);    // 94.4 MB
    float* h32    = (float*)alloc((size_t)BP * H_ * 4);      //  1.6 MB
    f16*   h16a   = (f16*)alloc((size_t)BP * H_ * 2);
    f16*   h16b   = (f16*)alloc((size_t)BP * H_ * 2);
    f16*   hid16  = (f16*)alloc((size_t)M_ * H_ * 2);        // 31.5 MB
    (void)ws_size; (void)in_sizes; (void)n_in; (void)out_size;

    // fp32 -> fp16 packs
    cvt_f32_f16<<<(M_ * E_) / 2048, 256, 0, stream>>>(feature, feat16, (M_ * E_) / 8);
    cvt_f32_f16<<<(H_ * E_) / 2048, 256, 0, stream>>>(W_embed, wE16, (H_ * E_) / 8);
    cvt_f32_f16<<<(3 * H_ * H_) / 2048, 256, 0, stream>>>(W_ih, wIH16, (3 * H_ * H_) / 8);
    cvt_f32_f16<<<(3 * H_ * H_) / 2048, 256, 0, stream>>>(W_hh, wHH16, (3 * H_ * H_) / 8);

    // embed: x = tanh(feat @ W_embed^T + b)
    gemm128<0><<<dim3(M_ / 128, H_ / 128), 256, 0, stream>>>(feat16, wE16, b_embed, x16, E_, H_);
    // gx = x @ W_ih^T + b_ih, remapped to [T][BP][3H]
    gemm128<1><<<dim3(M_ / 128, (3 * H_) / 128), 256, 0, stream>>>(x16, wIH16, b_ih, gx16, H_, 3 * H_);

    // h state = 0 (h32 fp32 + h16a fp16 are adjacent in ws)
    hipMemsetAsync(h32, 0, (size_t)BP * H_ * 4 + (size_t)BP * H_ * 2, stream);

    for (int t = 0; t < T_; ++t) {
        const f16* hin = (t & 1) ? h16b : h16a;
        f16* hout = (t & 1) ? h16a : h16b;
        gru_step<<<dim3(BP / 32, H_ / 64), 256, 0, stream>>>(hin, hout, h32, wHH16, b_hh,
                                                             gx16, hid16, t);
    }

    logits_kernel<<<B_ * T_, 256, 0, stream>>>(hid16, W_act, b_act, W_activ, b_activ, out);
}